// Round 8
// baseline (144.660 us; speedup 1.0000x reference)
//
#include <hip/hip_runtime.h>

// Problem constants (B, L, H, HS, OUT) = (4, 512, 768, 64, 16)
#define Bc   4
#define Lc   512
#define Hc   768
#define HSc  64
#define OUTc 16
#define Pc   131328   // L*(L+1)/2
#define NTOK 2048     // B*L
#define XPITCH 776    // 768 + 8 bf16 pad -> 16B-aligned rows, banks spread

typedef float  floatx4 __attribute__((ext_vector_type(4)));
typedef short  bf16x8  __attribute__((ext_vector_type(8)));   // 8 bf16 in 4 VGPRs
typedef float  f32x4   __attribute__((ext_vector_type(4)));

// ws layout (floats): q@0 [131072], k@131072 [131072], A@262144 [32768],
//   Eq@294912 [32768], Ek@327680 [32768], counter@360448 [1 u32]

__device__ __forceinline__ unsigned short f2bf(float f) {
    unsigned int u = __float_as_uint(f);
    return (unsigned short)((u + 0x7FFFu + ((u >> 16) & 1u)) >> 16);   // RNE
}

// Balanced single-kernel fusion. Session model (fits R0-R7 to +-1.5us):
// fixed harness cost ~67us, gap ~4us/boundary, qkae ~9, pair ~10.
// R4 failure = acquire-per-poll invalidate storm (fixed: relaxed spin + one
// acquire, proven in R5). R5 failure = only 44% of blocks produced (fixed
// here: ALL 256 blocks run one phase-1 unit).
// Grid 256 x 512 thr, 1 block/CU guaranteed resident (LDS 41KB <= 160KB,
// 8 waves <= 32) => spin barrier is deadlock-free by construction.
// Phase 1: block (mb=bx>>1, half=bx&1) = R2's qkae unit, but 8 waves with
// K-split-2 (waves 0-3 K in [0,384), waves 4-7 K in [384,768), LDS-reduce;
// fp32 reassociation only -> ulp-level vs R2). Then A/Eq/Ek projection
// (identical order to R2). Publish via __threadfence + release fetch_add.
// Barrier: lane0 relaxed-spins counter==256, ONE acquire, syncthreads.
// Phase 2: loop tiles bx, bx+256, bx+512 of the 576 pair tiles; body
// bit-identical to the R2 pair_kernel (tid<256 workers).
__global__ __launch_bounds__(512, 1) void fused_kernel(
    const float* __restrict__ x, const float* __restrict__ Wq,
    const float* __restrict__ Wk, const float* __restrict__ bq,
    const float* __restrict__ bk, const float* __restrict__ Wb,
    const float* __restrict__ bb,
    float* __restrict__ qws, float* __restrict__ kws,
    float* __restrict__ Aws, float* __restrict__ Eqws,
    float* __restrict__ Ekws, unsigned* __restrict__ counter,
    float* __restrict__ out)
{
    __shared__ alignas(16) unsigned char smem[41216];
    const int tid = threadIdx.x;
    const int bx  = blockIdx.x;

    // ---------------- Phase 1: QK GEMM + projections (all 256 blocks) ------
    {
        unsigned short* xs  = (unsigned short*)smem;       // 24832 B
        float* red = (float*)(smem + 24832);               // 4 KB  [4][64][4]
        float* lw0 = (float*)(smem + 28928);               // 4 KB
        float* lw1 = (float*)(smem + 33024);               // 4 KB
        float* lqk = (float*)(smem + 37120);               // 4 KB  [16][64]

        const int mb   = bx >> 1;
        const int half = bx & 1;           // 0 = q, 1 = k
        const int m0   = mb * 16;

        // stage Wb slices (1024 floats each, 512 thr)
        if (half == 0) {
            #pragma unroll
            for (int i = 0; i < 2; ++i) {
                lw0[tid + i * 512] = Wb[tid + i * 512];           // rows 0..63   (A)
                lw1[tid + i * 512] = Wb[2048 + tid + i * 512];    // rows 128..191(Eq)
            }
        } else {
            #pragma unroll
            for (int i = 0; i < 2; ++i)                            // rows 64..127 + 192..255
                lw0[tid + i * 512] = Wb[1024 + tid + i * 512] + Wb[3072 + tid + i * 512];
        }

        // stage x tile as bf16 (3072 float4 over 512 thr)
        {
            const float4* xg = (const float4*)(x + (size_t)m0 * Hc);
            #pragma unroll
            for (int i = 0; i < 6; ++i) {
                const int idx = tid + i * 512;
                const int r   = idx / 192;           // row 0..15
                const int c4  = idx - r * 192;       // float4 col 0..191
                const float4 v = xg[idx];
                *(ushort4*)(xs + r * XPITCH + c4 * 4) =
                    make_ushort4(f2bf(v.x), f2bf(v.y), f2bf(v.z), f2bf(v.w));
            }
        }
        __syncthreads();

        const int w    = tid >> 6;
        const int lane = tid & 63;
        const int l15  = lane & 15;
        const int quad = lane >> 4;
        const int ns   = w & 3;              // n-subtile 0..3
        const int kh   = w >> 2;             // K half 0..1
        const int nq   = ns * 16 + l15;      // output col 0..63 within this half
        const int kb0  = kh * 384;

        const float* bsrc = half ? Wk : Wq;
        const unsigned short* ap = xs + l15 * XPITCH + kb0 + quad * 8;

        f32x4 acc = {0.f, 0.f, 0.f, 0.f};
        #pragma unroll
        for (int s = 0; s < 12; ++s) {
            const bf16x8 a = *(const bf16x8*)(ap + s * 32);
            const int kg = kb0 + s * 32 + quad * 8;
            bf16x8 b;
            #pragma unroll
            for (int j = 0; j < 8; ++j)                            // quad-coalesced dwords
                b[j] = (short)f2bf(bsrc[(kg + j) * HSc + nq]);
            acc = __builtin_amdgcn_mfma_f32_16x16x32_bf16(a, b, acc, 0, 0, 0);
        }

        // K-split reduce: wave kh=1 parks partials, kh=0 sums
        if (kh == 1)
            *(f32x4*)(red + (ns * 64 + lane) * 4) = acc;
        __syncthreads();
        if (kh == 0) {
            const f32x4 p = *(const f32x4*)(red + (ns * 64 + lane) * 4);
            acc += p;
            const float bias = half ? bk[nq] : bq[nq];
            float* dst = half ? kws : qws;
            #pragma unroll
            for (int r = 0; r < 4; ++r) {
                const int t = quad * 4 + r;
                const float v = acc[r] + bias;
                dst[(size_t)(m0 + t) * HSc + nq] = v;
                lqk[t * 64 + nq] = v;
            }
        }
        __syncthreads();

        // projection epilogue (R2 order): 16 threads per token
        if (tid < 256) {
            const int t   = tid >> 4;
            const int c   = tid & 15;
            const int tok = m0 + t;
            const float* row = lqk + t * 64;
            if (half == 0) {
                float a = 0.f, eq = 0.f;
                #pragma unroll 8
                for (int h = 0; h < 64; ++h) {
                    const float rv = row[h];
                    a  += rv * lw0[h * OUTc + c];
                    eq += rv * lw1[h * OUTc + c];
                }
                Aws[(size_t)tok * OUTc + c]  = a;
                Eqws[(size_t)tok * OUTc + c] = eq;
            } else {
                float ek = bb[c];
                #pragma unroll 8
                for (int h = 0; h < 64; ++h)
                    ek += row[h] * lw0[h * OUTc + c];
                Ekws[(size_t)tok * OUTc + c] = ek;
            }
        }

        // publish (R5-proven protocol)
        __threadfence();
        __syncthreads();
        if (tid == 0)
            __hip_atomic_fetch_add(counter, 1u, __ATOMIC_RELEASE,
                                   __HIP_MEMORY_SCOPE_AGENT);
    }

    // ---------------- Global barrier (relaxed spin + single acquire) -------
    if (tid == 0) {
        while (__hip_atomic_load(counter, __ATOMIC_RELAXED,
                                 __HIP_MEMORY_SCOPE_AGENT) < 256u)
            __builtin_amdgcn_s_sleep(8);
        (void)__hip_atomic_load(counter, __ATOMIC_ACQUIRE,
                                __HIP_MEMORY_SCOPE_AGENT);
    }
    __syncthreads();

    // ---------------- Phase 2: pair assembly, tiles bx, bx+256, bx+512 -----
    {
        float* q_tile = (float*)smem;            // [16][64]
        float* A_tile = (float*)(smem + 4096);   // [16][16]

        for (int tt = bx; tt < 576; tt += 256) {
            __syncthreads();                      // LDS reuse across iterations

            const int b = tt / 144;
            int n = tt % 144;
            int g = 0;
            int cnt = 32;                         // 4*(8-g)
            while (n >= cnt) { n -= cnt; ++g; cnt = 4 * (8 - g); }
            const int span = 8 - g;
            const int i = g * 4 + n / span;
            const int j = g + n % span;
            const int s0 = i * 16;
            const int e0 = j * 64;

            if (tid < 256) {
                const int r = tid >> 4, c4 = tid & 15;
                ((float4*)(q_tile + r * 64))[c4] =
                    ((const float4*)(qws + ((size_t)b * Lc + s0 + r) * HSc))[c4];
                if (tid < 64) {
                    const int ra = tid >> 2, ca = tid & 3;
                    ((float4*)(A_tile + ra * 16))[ca] =
                        ((const float4*)(Aws + ((size_t)b * Lc + s0 + ra) * OUTc))[ca];
                }
            }
            __syncthreads();

            if (tid < 256) {
                const int gidx = tid >> 2;
                const int l = tid & 3;
                const int e = e0 + gidx;

                const float4* kk = (const float4*)(kws + ((size_t)b * Lc + e) * HSc);
                const float4 kv0 = kk[l];
                const float4 kv1 = kk[4 + l];
                const float4 kv2 = kk[8 + l];
                const float4 kv3 = kk[12 + l];
                const float4 evq = ((const float4*)(Eqws + ((size_t)b * Lc + e) * OUTc))[l];
                const float4 evk = ((const float4*)(Ekws + ((size_t)b * Lc + e) * OUTc))[l];
                const float4 ev  = make_float4(evq.x + evk.x, evq.y + evk.y,
                                               evq.z + evk.z, evq.w + evk.w);

                float* ob = out + (size_t)b * Pc * OUTc;

                #pragma unroll 8
                for (int sl = 0; sl < 16; ++sl) {
                    const int s = s0 + sl;
                    const float4* qq = (const float4*)(q_tile + sl * 64);
                    const float4 qv0 = qq[l];
                    const float4 qv1 = qq[4 + l];
                    const float4 qv2 = qq[8 + l];
                    const float4 qv3 = qq[12 + l];

                    float sc = qv0.x * kv0.x + qv0.y * kv0.y + qv0.z * kv0.z + qv0.w * kv0.w
                             + qv1.x * kv1.x + qv1.y * kv1.y + qv1.z * kv1.z + qv1.w * kv1.w
                             + qv2.x * kv2.x + qv2.y * kv2.y + qv2.z * kv2.z + qv2.w * kv2.w
                             + qv3.x * kv3.x + qv3.y * kv3.y + qv3.z * kv3.z + qv3.w * kv3.w;
                    sc += __shfl_xor(sc, 1);
                    sc += __shfl_xor(sc, 2);

                    if (e >= s) {
                        const float4 av = ((const float4*)(A_tile + sl * 16))[l];
                        const int row = s * (2 * Lc + 1 - s) / 2 + (e - s);
                        floatx4 r;
                        r.x = av.x + ev.x + sc;
                        r.y = av.y + ev.y + sc;
                        r.z = av.z + ev.z + sc;
                        r.w = av.w + ev.w + sc;
                        __builtin_nontemporal_store(r, (floatx4*)(ob + (size_t)row * OUTc) + l);
                    }
                }
            }
        }
    }
}

extern "C" void kernel_launch(void* const* d_in, const int* in_sizes, int n_in,
                              void* d_out, int out_size, void* d_ws, size_t ws_size,
                              hipStream_t stream) {
    const float* x  = (const float*)d_in[0];
    const float* Wq = (const float*)d_in[1];
    const float* bq = (const float*)d_in[2];
    const float* Wk = (const float*)d_in[3];
    const float* bk = (const float*)d_in[4];
    const float* Wb = (const float*)d_in[5];
    const float* bb = (const float*)d_in[6];

    float* ws   = (float*)d_ws;
    float* qws  = ws;
    float* kws  = ws + 131072;
    float* Aws  = ws + 262144;
    float* Eqws = ws + 294912;
    float* Ekws = ws + 327680;
    unsigned* counter = (unsigned*)(ws + 360448);

    hipMemsetAsync(counter, 0, sizeof(unsigned), stream);
    fused_kernel<<<dim3(256), dim3(512), 0, stream>>>(
        x, Wq, Wk, bq, bk, Wb, bb, qws, kws, Aws, Eqws, Ekws, counter,
        (float*)d_out);
}

// Round 9
// 90.826 us; speedup vs baseline: 1.5927x; 1.5927x over previous
//
#include <hip/hip_runtime.h>

// Problem constants (B, L, H, HS, OUT) = (4, 512, 768, 64, 16)
#define Bc   4
#define Lc   512
#define Hc   768
#define HSc  64
#define OUTc 16
#define Pc   131328   // L*(L+1)/2
#define NTOK 2048     // B*L
#define XPITCH 776    // 768 + 8 bf16 pad -> 16B-aligned rows, banks spread

typedef float  floatx4 __attribute__((ext_vector_type(4)));
typedef short  bf16x8  __attribute__((ext_vector_type(8)));   // 8 bf16 in 4 VGPRs
typedef float  f32x4   __attribute__((ext_vector_type(4)));

// ws layout (floats): q@0 [131072], k@131072 [131072], A@262144 [32768],
//                     Eq@294912 [32768], Ek@327680 [32768]

__device__ __forceinline__ unsigned short f2bf(float f) {
    unsigned int u = __float_as_uint(f);
    return (unsigned short)((u + 0x7FFFu + ((u >> 16) & 1u)) >> 16);   // RNE
}

// Fused prep + QK-GEMM + A/E projection, q/k-split for full-CU parallelism.
// Grid 256 x 256 thr (4 waves). Block bx: mb = bx>>1 (16-token tile),
// half = bx&1 (0 = q side, 1 = k side).
// Each block stages its x-tile as bf16 in LDS (coalesced float4 + RNE cvt),
// runs a 16x64 MFMA GEMM vs Wq or Wk (B-fragments converted in-register from
// global, L2-resident), then projects:
//   q-block: A  = q @ Wb[0:64]        ; Eq = q @ Wb[128:192]
//   k-block: Ek = bb + k @ (Wb[64:128] + Wb[192:256])
// pair_kernel sums Eq[e] + Ek[e] (pure fp32 reassociation vs the fused E).
// MFMA layouts (m89/m91): A[m=lane&15][k=quad*8+j]; B[k=quad*8+j][n=lane&15];
// D: col=lane&15, row=quad*4+reg.
// Session history (R0-R8): this two-kernel structure is the measured floor.
// Three single-kernel fusion attempts (grid.sync R3, flag-gated R4/R5,
// balanced+counter-barrier R8) all regressed 20-60us: intra-kernel cross-XCD
// sync + lost inter-dispatch L2 warmth + spin-idle cost more than the ~4us
// dispatch boundary they remove. Do not re-attempt fusion on this harness.
__global__ __launch_bounds__(256) void qkae_kernel(
    const float* __restrict__ x, const float* __restrict__ Wq,
    const float* __restrict__ Wk, const float* __restrict__ bq,
    const float* __restrict__ bk, const float* __restrict__ Wb,
    const float* __restrict__ bb,
    float* __restrict__ qws, float* __restrict__ kws,
    float* __restrict__ Aws, float* __restrict__ Eqws,
    float* __restrict__ Ekws)
{
    __shared__ alignas(16) unsigned short xs[16 * XPITCH];  // 24.25 KB
    __shared__ float lw0[64 * OUTc];                        // 4 KB
    __shared__ float lw1[64 * OUTc];                        // 4 KB
    __shared__ float lqk[16][64];                           // 4 KB

    const int tid  = threadIdx.x;
    const int mb   = blockIdx.x >> 1;
    const int half = blockIdx.x & 1;       // 0 = q, 1 = k
    const int m0   = mb * 16;

    // stage Wb slices (1024 floats each)
    if (half == 0) {
        #pragma unroll
        for (int i = 0; i < 4; ++i) {
            lw0[tid + i * 256] = Wb[tid + i * 256];           // rows 0..63   (A)
            lw1[tid + i * 256] = Wb[2048 + tid + i * 256];    // rows 128..191(Eq)
        }
    } else {
        #pragma unroll
        for (int i = 0; i < 4; ++i) {                          // rows 64..127 + 192..255
            lw0[tid + i * 256] = Wb[1024 + tid + i * 256] + Wb[3072 + tid + i * 256];
        }
    }

    // stage x tile as bf16 into padded LDS rows (3072 float4 total)
    {
        const float4* xg = (const float4*)(x + (size_t)m0 * Hc);
        #pragma unroll
        for (int i = 0; i < 12; ++i) {
            const int idx = tid + i * 256;
            const int r   = idx / 192;           // row 0..15
            const int c4  = idx - r * 192;       // float4 col 0..191
            const float4 v = xg[idx];
            *(ushort4*)(xs + r * XPITCH + c4 * 4) =
                make_ushort4(f2bf(v.x), f2bf(v.y), f2bf(v.z), f2bf(v.w));
        }
    }
    __syncthreads();

    const int w    = tid >> 6;
    const int lane = tid & 63;
    const int l15  = lane & 15;
    const int quad = lane >> 4;
    const int nq   = w * 16 + l15;           // output col 0..63 within this half

    const float* bsrc = half ? Wk : Wq;
    const unsigned short* ap = xs + l15 * XPITCH + quad * 8;

    f32x4 acc = {0.f, 0.f, 0.f, 0.f};
    #pragma unroll 4
    for (int k0 = 0; k0 < Hc; k0 += 32) {
        const bf16x8 af = *(const bf16x8*)(ap + k0);       // ds_read_b128
        const int kb = k0 + quad * 8;
        bf16x8 bf;
        #pragma unroll
        for (int j = 0; j < 8; ++j)                        // quad-coalesced dwords
            bf[j] = (short)f2bf(bsrc[(kb + j) * HSc + nq]);
        acc = __builtin_amdgcn_mfma_f32_16x16x32_bf16(af, bf, acc, 0, 0, 0);
    }

    const float bias = half ? bk[nq] : bq[nq];
    float* dst = half ? kws : qws;
    #pragma unroll
    for (int r = 0; r < 4; ++r) {
        const int t = quad * 4 + r;
        const float v = acc[r] + bias;
        dst[(size_t)(m0 + t) * HSc + nq] = v;
        lqk[t][nq] = v;
    }
    __syncthreads();

    // projection epilogue: 16 threads per token, one output col each
    const int t   = tid >> 4;        // token 0..15
    const int c   = tid & 15;
    const int tok = m0 + t;
    const float* row = lqk[t];
    if (half == 0) {
        float a = 0.f, eq = 0.f;
        #pragma unroll 8
        for (int h = 0; h < 64; ++h) {
            const float rv = row[h];
            a  += rv * lw0[h * OUTc + c];
            eq += rv * lw1[h * OUTc + c];
        }
        Aws[(size_t)tok * OUTc + c]  = a;
        Eqws[(size_t)tok * OUTc + c] = eq;
    } else {
        float ek = bb[c];
        #pragma unroll 8
        for (int h = 0; h < 64; ++h)
            ek += row[h] * lw0[h * OUTc + c];
        Ekws[(size_t)tok * OUTc + c] = ek;
    }
}

// Pair kernel: 16 s x 64 e tiles, only the 144 active upper-triangular tiles
// per batch (decoded in-kernel). Grid (144, 4): x = linear tile id, y = batch.
__global__ __launch_bounds__(256) void pair_kernel(
    const float* __restrict__ qws, const float* __restrict__ kws,
    const float* __restrict__ Aws, const float* __restrict__ Eqws,
    const float* __restrict__ Ekws,
    float* __restrict__ out)
{
    // decode linear tile id -> (i = s-tile 0..31, j = e-tile 0..7), j >= i>>2
    int n = blockIdx.x;
    int g = 0;
    int cnt = 32;                       // 4*(8-g)
    while (n >= cnt) { n -= cnt; ++g; cnt = 4 * (8 - g); }
    const int span = 8 - g;
    const int i = g * 4 + n / span;
    const int j = g + n % span;
    const int b = blockIdx.y;

    __shared__ alignas(16) float q_tile[16][64];
    __shared__ alignas(16) float A_tile[16][16];

    const int tid = threadIdx.x;
    const int s0 = i * 16;
    const int e0 = j * 64;

    {
        const int r = tid >> 4, c4 = tid & 15;
        ((float4*)q_tile[r])[c4] =
            ((const float4*)(qws + ((size_t)b * Lc + s0 + r) * HSc))[c4];
        if (tid < 64) {
            const int ra = tid >> 2, ca = tid & 3;
            ((float4*)A_tile[ra])[ca] =
                ((const float4*)(Aws + ((size_t)b * Lc + s0 + ra) * OUTc))[ca];
        }
    }
    __syncthreads();

    const int gidx = tid >> 2;
    const int l = tid & 3;
    const int e = e0 + gidx;

    const float4* kk = (const float4*)(kws + ((size_t)b * Lc + e) * HSc);
    const float4 kv0 = kk[l];
    const float4 kv1 = kk[4 + l];
    const float4 kv2 = kk[8 + l];
    const float4 kv3 = kk[12 + l];
    const float4 evq = ((const float4*)(Eqws + ((size_t)b * Lc + e) * OUTc))[l];
    const float4 evk = ((const float4*)(Ekws + ((size_t)b * Lc + e) * OUTc))[l];
    const float4 ev  = make_float4(evq.x + evk.x, evq.y + evk.y,
                                   evq.z + evk.z, evq.w + evk.w);

    float* ob = out + (size_t)b * Pc * OUTc;

    #pragma unroll 8
    for (int sl = 0; sl < 16; ++sl) {
        const int s = s0 + sl;
        const float4* qq = (const float4*)q_tile[sl];
        const float4 qv0 = qq[l];
        const float4 qv1 = qq[4 + l];
        const float4 qv2 = qq[8 + l];
        const float4 qv3 = qq[12 + l];

        float sc = qv0.x * kv0.x + qv0.y * kv0.y + qv0.z * kv0.z + qv0.w * kv0.w
                 + qv1.x * kv1.x + qv1.y * kv1.y + qv1.z * kv1.z + qv1.w * kv1.w
                 + qv2.x * kv2.x + qv2.y * kv2.y + qv2.z * kv2.z + qv2.w * kv2.w
                 + qv3.x * kv3.x + qv3.y * kv3.y + qv3.z * kv3.z + qv3.w * kv3.w;
        sc += __shfl_xor(sc, 1);
        sc += __shfl_xor(sc, 2);

        if (e >= s) {
            const float4 av = ((const float4*)A_tile[sl])[l];
            const int row = s * (2 * Lc + 1 - s) / 2 + (e - s);
            floatx4 r;
            r.x = av.x + ev.x + sc;
            r.y = av.y + ev.y + sc;
            r.z = av.z + ev.z + sc;
            r.w = av.w + ev.w + sc;
            __builtin_nontemporal_store(r, (floatx4*)(ob + (size_t)row * OUTc) + l);
        }
    }
}

extern "C" void kernel_launch(void* const* d_in, const int* in_sizes, int n_in,
                              void* d_out, int out_size, void* d_ws, size_t ws_size,
                              hipStream_t stream) {
    const float* x  = (const float*)d_in[0];
    const float* Wq = (const float*)d_in[1];
    const float* bq = (const float*)d_in[2];
    const float* Wk = (const float*)d_in[3];
    const float* bk = (const float*)d_in[4];
    const float* Wb = (const float*)d_in[5];
    const float* bb = (const float*)d_in[6];

    float* ws   = (float*)d_ws;
    float* qws  = ws;
    float* kws  = ws + 131072;
    float* Aws  = ws + 262144;
    float* Eqws = ws + 294912;
    float* Ekws = ws + 327680;

    qkae_kernel<<<dim3(256), dim3(256), 0, stream>>>(
        x, Wq, Wk, bq, bk, Wb, bb, qws, kws, Aws, Eqws, Ekws);
    pair_kernel<<<dim3(144, 4), dim3(256), 0, stream>>>(
        qws, kws, Aws, Eqws, Ekws, (float*)d_out);
}